// Round 1
// baseline (524.585 us; speedup 1.0000x reference)
//
#include <hip/hip_runtime.h>
#include <hip/hip_bf16.h>

#define NN 100000
#define NE 1600000
#define DIN 128
#define NG 512
#define MAXD 64
#define NBUK 391               // dst>>8 buckets (256 nodes each)
#define BCAP 5120              // mean 4092, +16 sigma
#define CHUNK ((NE + NBUK - 1) / NBUK)

// ============ fused: phase-1 binning (blocks 0..NBUK) || input GEMM (rest) ============
// input GEMM: float4 k-packed LDS weights (ds_read_b128), 8 nodes/wave, 32 fma per LDS read.
#define GB 512
__global__ void __launch_bounds__(512) k_front(const int* __restrict__ src,
                                               const int* __restrict__ dst,
                                               int* __restrict__ cursor,
                                               unsigned int* __restrict__ bucket,
                                               const float* __restrict__ x,
                                               const float* __restrict__ W0,
                                               const float* __restrict__ b0,
                                               float* __restrict__ h) {
    __shared__ float4 sW4[32 * 64];   // sW4[kk*64+ln] = {W0[4kk..4kk+3][ln]}, 32 KB
    __shared__ int lcnt[NBUK];
    __shared__ int lbase[NBUK];
    if (blockIdx.x < NBUK) {
        // ---- bin edges by dst>>8 via LDS histogram; 1 global atomic per (block,bucket) ----
        for (int i = threadIdx.x; i < NBUK; i += 512) lcnt[i] = 0;
        __syncthreads();
        int e0 = blockIdx.x * CHUNK;
        int e1 = min(e0 + CHUNK, NE);
        for (int e = e0 + (int)threadIdx.x; e < e1; e += 512)
            atomicAdd(&lcnt[dst[e] >> 8], 1);
        __syncthreads();
        for (int i = threadIdx.x; i < NBUK; i += 512) {
            int c = lcnt[i];
            lbase[i] = c ? atomicAdd(&cursor[i], c) : 0;
            lcnt[i] = 0;
        }
        __syncthreads();
        for (int e = e0 + (int)threadIdx.x; e < e1; e += 512) {
            int d = dst[e];
            int s = src[e];
            int bk = d >> 8;
            int pos = lbase[bk] + atomicAdd(&lcnt[bk], 1);
            if (pos < BCAP)
                bucket[(size_t)bk * BCAP + pos] = ((unsigned)s << 8) | (unsigned)(d & 255);
        }
    } else {
        // ---- input GEMM: h = relu(x @ W0 + b0) ----
        for (int i = threadIdx.x; i < 32 * 64; i += 512) {
            const float* wp = W0 + (i >> 6) * 256 + (i & 63);
            sW4[i] = make_float4(wp[0], wp[64], wp[128], wp[192]);
        }
        __syncthreads();
        int lane = threadIdx.x & 63;
        int wv   = __builtin_amdgcn_readfirstlane(
                       (int)(((blockIdx.x - NBUK) * 512 + threadIdx.x) >> 6));
        int nw   = (GB * 512) >> 6;
        float bj = b0[lane];
        for (int p = wv; p < NN / 8; p += nw) {
            const float* xb = x + (size_t)(8 * p) * DIN;   // wave-uniform -> s_load
            float a0 = bj, a1 = bj, a2 = bj, a3 = bj;
            float a4 = bj, a5 = bj, a6 = bj, a7 = bj;
#pragma unroll 2
            for (int kk = 0; kk < 32; ++kk) {
                float4 w = sW4[kk * 64 + lane];
                int k = kk * 4;
                a0 = fmaf(xb[k      ], w.x, a0); a0 = fmaf(xb[k +   1], w.y, a0);
                a0 = fmaf(xb[k +   2], w.z, a0); a0 = fmaf(xb[k +   3], w.w, a0);
                a1 = fmaf(xb[k + 128], w.x, a1); a1 = fmaf(xb[k + 129], w.y, a1);
                a1 = fmaf(xb[k + 130], w.z, a1); a1 = fmaf(xb[k + 131], w.w, a1);
                a2 = fmaf(xb[k + 256], w.x, a2); a2 = fmaf(xb[k + 257], w.y, a2);
                a2 = fmaf(xb[k + 258], w.z, a2); a2 = fmaf(xb[k + 259], w.w, a2);
                a3 = fmaf(xb[k + 384], w.x, a3); a3 = fmaf(xb[k + 385], w.y, a3);
                a3 = fmaf(xb[k + 386], w.z, a3); a3 = fmaf(xb[k + 387], w.w, a3);
                a4 = fmaf(xb[k + 512], w.x, a4); a4 = fmaf(xb[k + 513], w.y, a4);
                a4 = fmaf(xb[k + 514], w.z, a4); a4 = fmaf(xb[k + 515], w.w, a4);
                a5 = fmaf(xb[k + 640], w.x, a5); a5 = fmaf(xb[k + 641], w.y, a5);
                a5 = fmaf(xb[k + 642], w.z, a5); a5 = fmaf(xb[k + 643], w.w, a5);
                a6 = fmaf(xb[k + 768], w.x, a6); a6 = fmaf(xb[k + 769], w.y, a6);
                a6 = fmaf(xb[k + 770], w.z, a6); a6 = fmaf(xb[k + 771], w.w, a6);
                a7 = fmaf(xb[k + 896], w.x, a7); a7 = fmaf(xb[k + 897], w.y, a7);
                a7 = fmaf(xb[k + 898], w.z, a7); a7 = fmaf(xb[k + 899], w.w, a7);
            }
            size_t base = (size_t)(8 * p) * 64 + lane;
            h[base      ] = fmaxf(a0, 0.0f);
            h[base +  64] = fmaxf(a1, 0.0f);
            h[base + 128] = fmaxf(a2, 0.0f);
            h[base + 192] = fmaxf(a3, 0.0f);
            h[base + 256] = fmaxf(a4, 0.0f);
            h[base + 320] = fmaxf(a5, 0.0f);
            h[base + 384] = fmaxf(a6, 0.0f);
            h[base + 448] = fmaxf(a7, 0.0f);
        }
    }
}

// ---- gemmLR body: g(bf16) = h@Wl ; r(fp32,in-place) = h@Wr + bl ----
// float4 k-packed weights in LDS: {Wl[k],Wr[k],Wl[k+1],Wr[k+1]} -> 1 ds_read_b128
// feeds 32 fma (8 nodes/wave x 2 outputs x 2 k).
__device__ __forceinline__ void gemmLR_body(float4* sW, int tid, int nblk, int bidx,
                                            float* __restrict__ h_r,
                                            __hip_bfloat16* __restrict__ g,
                                            const float* __restrict__ Wl,
                                            const float* __restrict__ bl,
                                            const float* __restrict__ Wr) {
    for (int i = tid; i < 32 * 64; i += 256) {
        int o = (i >> 6) * 128 + (i & 63);
        sW[i] = make_float4(Wl[o], Wr[o], Wl[o + 64], Wr[o + 64]);
    }
    __syncthreads();
    int lane = tid & 63;
    float bj = bl[lane];
    int wv = __builtin_amdgcn_readfirstlane((int)((bidx * 256 + tid) >> 6));
    int nw = nblk * 4;
    for (int q = wv; q < NN / 8; q += nw) {
        const float* hp = h_r + (size_t)(8 * q) * 64;   // wave-uniform -> s_load
        float l0 = 0, l1 = 0, l2 = 0, l3 = 0, l4 = 0, l5 = 0, l6 = 0, l7 = 0;
        float r0 = 0, r1 = 0, r2 = 0, r3 = 0, r4 = 0, r5 = 0, r6 = 0, r7 = 0;
#pragma unroll 4
        for (int kk = 0; kk < 32; ++kk) {
            float4 w = sW[kk * 64 + lane];
            int k = 2 * kk;
            float s0 = hp[k      ], t0 = hp[k +   1];
            float s1 = hp[k +  64], t1 = hp[k +  65];
            float s2 = hp[k + 128], t2 = hp[k + 129];
            float s3 = hp[k + 192], t3 = hp[k + 193];
            float s4 = hp[k + 256], t4 = hp[k + 257];
            float s5 = hp[k + 320], t5 = hp[k + 321];
            float s6 = hp[k + 384], t6 = hp[k + 385];
            float s7 = hp[k + 448], t7 = hp[k + 449];
            l0 = fmaf(s0, w.x, l0); r0 = fmaf(s0, w.y, r0);
            l0 = fmaf(t0, w.z, l0); r0 = fmaf(t0, w.w, r0);
            l1 = fmaf(s1, w.x, l1); r1 = fmaf(s1, w.y, r1);
            l1 = fmaf(t1, w.z, l1); r1 = fmaf(t1, w.w, r1);
            l2 = fmaf(s2, w.x, l2); r2 = fmaf(s2, w.y, r2);
            l2 = fmaf(t2, w.z, l2); r2 = fmaf(t2, w.w, r2);
            l3 = fmaf(s3, w.x, l3); r3 = fmaf(s3, w.y, r3);
            l3 = fmaf(t3, w.z, l3); r3 = fmaf(t3, w.w, r3);
            l4 = fmaf(s4, w.x, l4); r4 = fmaf(s4, w.y, r4);
            l4 = fmaf(t4, w.z, l4); r4 = fmaf(t4, w.w, r4);
            l5 = fmaf(s5, w.x, l5); r5 = fmaf(s5, w.y, r5);
            l5 = fmaf(t5, w.z, l5); r5 = fmaf(t5, w.w, r5);
            l6 = fmaf(s6, w.x, l6); r6 = fmaf(s6, w.y, r6);
            l6 = fmaf(t6, w.z, l6); r6 = fmaf(t6, w.w, r6);
            l7 = fmaf(s7, w.x, l7); r7 = fmaf(s7, w.y, r7);
            l7 = fmaf(t7, w.z, l7); r7 = fmaf(t7, w.w, r7);
        }
        size_t base = (size_t)(8 * q) * 64 + lane;
        g[base      ] = __float2bfloat16(l0);  h_r[base      ] = r0 + bj;
        g[base +  64] = __float2bfloat16(l1);  h_r[base +  64] = r1 + bj;
        g[base + 128] = __float2bfloat16(l2);  h_r[base + 128] = r2 + bj;
        g[base + 192] = __float2bfloat16(l3);  h_r[base + 192] = r3 + bj;
        g[base + 256] = __float2bfloat16(l4);  h_r[base + 256] = r4 + bj;
        g[base + 320] = __float2bfloat16(l5);  h_r[base + 320] = r5 + bj;
        g[base + 384] = __float2bfloat16(l6);  h_r[base + 384] = r6 + bj;
        g[base + 448] = __float2bfloat16(l7);  h_r[base + 448] = r7 + bj;
    }
}

// ============ fused: phase-2 ELL build (blocks 0..NBUK) || gemmLR layer 0 ============
#define MGB 1024
__global__ void __launch_bounds__(256) k_mid(const unsigned int* __restrict__ bucket,
                                             const int* __restrict__ cursor,
                                             int* __restrict__ cnt,
                                             int* __restrict__ ell,
                                             float* __restrict__ h_r,
                                             __hip_bfloat16* __restrict__ g,
                                             const float* __restrict__ Wl,
                                             const float* __restrict__ bl,
                                             const float* __restrict__ Wr) {
    __shared__ float4 sW[32 * 64];
    __shared__ int lc[256];
    if (blockIdx.x < NBUK) {
        lc[threadIdx.x] = 0;
        int b = blockIdx.x;
        int4* ep = (int4*)(ell + (((size_t)b << 8) * MAXD));
        for (int i = threadIdx.x; i < (256 * MAXD) / 4; i += 256)
            ep[i] = make_int4(NN, NN, NN, NN);          // sentinel -> zero row of G
        __syncthreads();
        int m = min(cursor[b], BCAP);
        const unsigned int* bp = bucket + (size_t)b * BCAP;
        for (int i = threadIdx.x; i < m; i += 256) {
            unsigned v = bp[i];
            int dlo = (int)(v & 255u);
            int s   = (int)(v >> 8);
            int p   = atomicAdd(&lc[dlo], 1);           // LDS atomic
            if (p < MAXD)
                ell[(((size_t)b << 8) + dlo) * MAXD + p] = s;
        }
        __syncthreads();
        int n = (b << 8) + (int)threadIdx.x;
        if (n < NN) cnt[n] = lc[threadIdx.x];
    } else {
        gemmLR_body(sW, threadIdx.x, MGB, blockIdx.x - NBUK, h_r, g, Wl, bl, Wr);
    }
}

// ============ standalone gemmLR (layers 1,2) ============
__global__ void __launch_bounds__(256) k_gemmLR(float* __restrict__ h_r,
                                                __hip_bfloat16* __restrict__ g,
                                                const float* __restrict__ Wl,
                                                const float* __restrict__ bl,
                                                const float* __restrict__ Wr) {
    __shared__ float4 sW[32 * 64];
    gemmLR_body(sW, threadIdx.x, gridDim.x, blockIdx.x, h_r, g, Wl, bl, Wr);
}

// ============ gather: 2 nodes/wave, 4 B/lane (bf16x2), sentinel-padded, 8-way ILP ====
__global__ void __launch_bounds__(256) k_gather(const unsigned int* __restrict__ g2,
                                                float* __restrict__ r_h,
                                                const int* __restrict__ cnt,
                                                const int* __restrict__ ell) {
    int lane = threadIdx.x & 63;
    int half = lane >> 5;
    int col  = lane & 31;
    int wv = __builtin_amdgcn_readfirstlane((int)((blockIdx.x * 256 + threadIdx.x) >> 6));
    int nw = (gridDim.x * 256) >> 6;
    for (int p = wv; p < NN / 2; p += nw) {
        int nA = 2 * p, nB = nA + 1;
        int dgA = cnt[nA], dgB = cnt[nB];               // wave-uniform scalar loads
        int myn  = half ? nB : nA;
        int mydg = half ? dgB : dgA;
        int maxd = min(max(dgA, dgB), MAXD);
        int iters = (maxd + 7) & ~7;                    // pad to 8; sentinels add 0
        int idx0 = ell[(size_t)myn * MAXD + col];
        int idx1 = NN;
        if (iters > 32) idx1 = ell[(size_t)myn * MAXD + 32 + col];
        float L0=0.f,L1=0.f,L2=0.f,L3=0.f,L4=0.f,L5=0.f,L6=0.f,L7=0.f;
        float H0=0.f,H1=0.f,H2=0.f,H3=0.f,H4=0.f,H5=0.f,H6=0.f,H7=0.f;
        int it0 = min(iters, 32);
        for (int j = 0; j < it0; j += 8) {
            int i0 = __shfl(idx0, half * 32 + j);
            int i1 = __shfl(idx0, half * 32 + j + 1);
            int i2 = __shfl(idx0, half * 32 + j + 2);
            int i3 = __shfl(idx0, half * 32 + j + 3);
            int i4 = __shfl(idx0, half * 32 + j + 4);
            int i5 = __shfl(idx0, half * 32 + j + 5);
            int i6 = __shfl(idx0, half * 32 + j + 6);
            int i7 = __shfl(idx0, half * 32 + j + 7);
            unsigned u0 = g2[(size_t)i0 * 32 + col];
            unsigned u1 = g2[(size_t)i1 * 32 + col];
            unsigned u2 = g2[(size_t)i2 * 32 + col];
            unsigned u3 = g2[(size_t)i3 * 32 + col];
            unsigned u4 = g2[(size_t)i4 * 32 + col];
            unsigned u5 = g2[(size_t)i5 * 32 + col];
            unsigned u6 = g2[(size_t)i6 * 32 + col];
            unsigned u7 = g2[(size_t)i7 * 32 + col];
            L0 += __uint_as_float(u0 << 16); H0 += __uint_as_float(u0 & 0xffff0000u);
            L1 += __uint_as_float(u1 << 16); H1 += __uint_as_float(u1 & 0xffff0000u);
            L2 += __uint_as_float(u2 << 16); H2 += __uint_as_float(u2 & 0xffff0000u);
            L3 += __uint_as_float(u3 << 16); H3 += __uint_as_float(u3 & 0xffff0000u);
            L4 += __uint_as_float(u4 << 16); H4 += __uint_as_float(u4 & 0xffff0000u);
            L5 += __uint_as_float(u5 << 16); H5 += __uint_as_float(u5 & 0xffff0000u);
            L6 += __uint_as_float(u6 << 16); H6 += __uint_as_float(u6 & 0xffff0000u);
            L7 += __uint_as_float(u7 << 16); H7 += __uint_as_float(u7 & 0xffff0000u);
        }
        for (int j = 0; j < iters - 32; j += 8) {
            int i0 = __shfl(idx1, half * 32 + j);
            int i1 = __shfl(idx1, half * 32 + j + 1);
            int i2 = __shfl(idx1, half * 32 + j + 2);
            int i3 = __shfl(idx1, half * 32 + j + 3);
            int i4 = __shfl(idx1, half * 32 + j + 4);
            int i5 = __shfl(idx1, half * 32 + j + 5);
            int i6 = __shfl(idx1, half * 32 + j + 6);
            int i7 = __shfl(idx1, half * 32 + j + 7);
            unsigned u0 = g2[(size_t)i0 * 32 + col];
            unsigned u1 = g2[(size_t)i1 * 32 + col];
            unsigned u2 = g2[(size_t)i2 * 32 + col];
            unsigned u3 = g2[(size_t)i3 * 32 + col];
            unsigned u4 = g2[(size_t)i4 * 32 + col];
            unsigned u5 = g2[(size_t)i5 * 32 + col];
            unsigned u6 = g2[(size_t)i6 * 32 + col];
            unsigned u7 = g2[(size_t)i7 * 32 + col];
            L0 += __uint_as_float(u0 << 16); H0 += __uint_as_float(u0 & 0xffff0000u);
            L1 += __uint_as_float(u1 << 16); H1 += __uint_as_float(u1 & 0xffff0000u);
            L2 += __uint_as_float(u2 << 16); H2 += __uint_as_float(u2 & 0xffff0000u);
            L3 += __uint_as_float(u3 << 16); H3 += __uint_as_float(u3 & 0xffff0000u);
            L4 += __uint_as_float(u4 << 16); H4 += __uint_as_float(u4 & 0xffff0000u);
            L5 += __uint_as_float(u5 << 16); H5 += __uint_as_float(u5 & 0xffff0000u);
            L6 += __uint_as_float(u6 << 16); H6 += __uint_as_float(u6 & 0xffff0000u);
            L7 += __uint_as_float(u7 << 16); H7 += __uint_as_float(u7 & 0xffff0000u);
        }
        float inv  = 1.0f / fmaxf((float)mydg, 1.0f);
        float sumL = ((L0 + L1) + (L2 + L3)) + ((L4 + L5) + (L6 + L7));
        float sumH = ((H0 + H1) + (H2 + H3)) + ((H4 + H5) + (H6 + H7));
        float2* rp = (float2*)r_h + (size_t)myn * 32 + col;
        float2 rv = *rp;
        rv.x = fmaxf(fmaf(sumL, inv, rv.x), 0.0f);
        rv.y = fmaxf(fmaf(sumH, inv, rv.y), 0.0f);
        *rp = rv;
    }
}

// ============ pooling (batch sorted -> run accumulate) ============
__global__ void __launch_bounds__(256) k_pool(const int* __restrict__ batch,
                                              const float* __restrict__ h,
                                              float* __restrict__ pool,
                                              float* __restrict__ cntg) {
    int lane = threadIdx.x & 63;
    int wid  = (blockIdx.x * 256 + threadIdx.x) >> 6;
    int nw   = (gridDim.x * 256) >> 6;
    int chunk = (NN + nw - 1) / nw;
    int n0 = wid * chunk;
    if (n0 >= NN) return;
    int n1 = min(n0 + chunk, NN);
    int cur = batch[n0];
    float acc = 0.0f, acc_c = 0.0f;
    for (int n = n0; n < n1; ++n) {
        int b = batch[n];
        if (b != cur) {
            atomicAdd(&pool[(size_t)cur * 64 + lane], acc);
            if (lane == 0) atomicAdd(&cntg[cur], acc_c);
            acc = 0.0f; acc_c = 0.0f; cur = b;
        }
        acc   += h[(size_t)n * 64 + lane];
        acc_c += 1.0f;
    }
    atomicAdd(&pool[(size_t)cur * 64 + lane], acc);
    if (lane == 0) atomicAdd(&cntg[cur], acc_c);
}

// ============ output GEMM ============
__global__ void __launch_bounds__(256) k_out(const float* __restrict__ pool,
                                             const float* __restrict__ cntg,
                                             const float* __restrict__ W1,
                                             const float* __restrict__ b1,
                                             float* __restrict__ out) {
    __shared__ float sW[64 * 64];
    for (int i = threadIdx.x; i < 64 * 64; i += 256) sW[i] = W1[i];
    __syncthreads();
    int lane = threadIdx.x & 63;
    int wid  = (blockIdx.x * 256 + threadIdx.x) >> 6;
    int nw   = (gridDim.x * 256) >> 6;
    for (int gidx = wid; gidx < NG; gidx += nw) {
        float ic = 1.0f / fmaxf(cntg[gidx], 1.0f);
        float acc = 0.0f;
#pragma unroll
        for (int k = 0; k < 64; ++k)
            acc = fmaf(pool[(size_t)gidx * 64 + k], sW[k * 64 + lane], acc);
        out[(size_t)gidx * 64 + lane] = fmaf(acc, ic, b1[lane]);
    }
}

extern "C" void kernel_launch(void* const* d_in, const int* in_sizes, int n_in,
                              void* d_out, int out_size, void* d_ws, size_t ws_size,
                              hipStream_t stream) {
    const float* x     = (const float*)d_in[0];
    const int*   ei    = (const int*)d_in[1];   // [2,E]
    const int*   batch = (const int*)d_in[3];
    const float* W0    = (const float*)d_in[4];
    const float* b0    = (const float*)d_in[5];
    const float* Wl    = (const float*)d_in[6];
    const float* bl    = (const float*)d_in[7];
    const float* Wr    = (const float*)d_in[8];
    const float* W1    = (const float*)d_in[9];
    const float* b1    = (const float*)d_in[10];
    float* out = (float*)d_out;

    char* ws = (char*)d_ws;
    size_t off = 0;
    auto alloc = [&](size_t bytes) -> void* {
        void* p = ws + off;
        off += (bytes + 255) & ~(size_t)255;
        return p;
    };
    float*          A      = (float*)alloc((size_t)NN * 64 * 4);          // h / r / h'
    __hip_bfloat16* G      = (__hip_bfloat16*)alloc((size_t)NN * 64 * 2); // g (bf16), NN rows
    // zero region starts EXACTLY at G's row NN (sentinel zero row), then cursor/pool/cntg
    size_t zstart = off;
    (void)alloc((size_t)MAXD * 2);                                        // G zero row (128 B)
    int*   cursor = (int*)alloc((size_t)NBUK * 4);
    float* pool   = (float*)alloc((size_t)NG * 64 * 4);
    float* cntg   = (float*)alloc((size_t)NG * 4);
    size_t zlen = off - zstart;
    int*          ell    = (int*)alloc((size_t)NBUK * 256 * MAXD * 4);    // padded ELL
    unsigned int* bucket = (unsigned int*)alloc((size_t)NBUK * BCAP * 4);
    int*          cnt    = (int*)alloc((size_t)NN * 4);                   // fully written

    const int* src = ei;
    const int* dst = ei + NE;

    hipMemsetAsync(ws + zstart, 0, zlen, stream);

    // phase-1 binning || input projection
    k_front<<<NBUK + GB, 512, 0, stream>>>(src, dst, cursor, bucket, x, W0, b0, A);
    // phase-2 ELL build || gemmLR layer 0
    k_mid<<<NBUK + MGB, 256, 0, stream>>>(bucket, cursor, cnt, ell, A, G,
                                          Wl, bl, Wr);
    k_gather<<<4096, 256, 0, stream>>>((const unsigned int*)G, A, cnt, ell);

    for (int l = 1; l < 3; ++l) {
        k_gemmLR<<<1024, 256, 0, stream>>>(A, G,
                                           Wl + (size_t)l * 64 * 64,
                                           bl + (size_t)l * 64,
                                           Wr + (size_t)l * 64 * 64);
        k_gather<<<4096, 256, 0, stream>>>((const unsigned int*)G, A, cnt, ell);
    }

    k_pool<<<256, 256, 0, stream>>>(batch, A, pool, cntg);
    k_out<<<128, 256, 0, stream>>>(pool, cntg, W1, b1, out);
}

// Round 2
// 478.247 us; speedup vs baseline: 1.0969x; 1.0969x over previous
//
#include <hip/hip_runtime.h>
#include <hip/hip_bf16.h>

#define NN 100000
#define NE 1600000
#define DIN 128
#define NG 512
#define MAXD 64
#define NBUK 391               // dst>>8 buckets (256 nodes each)
#define BCAP 5120              // mean 4092, +16 sigma
#define CHUNK ((NE + NBUK - 1) / NBUK)
#define NTILE ((NN + 63) >> 6)  // 64-node tiles

static __device__ __forceinline__ unsigned short f2bf(float f) {
    __hip_bfloat16 h = __float2bfloat16(f);
    return *reinterpret_cast<unsigned short*>(&h);
}

// ============ fused: phase-1 binning (blocks 0..NBUK) || input GEMM (rest) ============
// input GEMM: lane=node. x staged to LDS via coalesced vector loads (T2 XOR swizzle),
// weights broadcast from LDS. NO scalar-path streaming (round-1 post-mortem: 51 MB of x
// through sK$ was the 90-118us bottleneck).
#define GB 512
__global__ void __launch_bounds__(512) k_front(const int* __restrict__ src,
                                               const int* __restrict__ dst,
                                               int* __restrict__ cursor,
                                               unsigned int* __restrict__ bucket,
                                               const float* __restrict__ x,
                                               const float* __restrict__ W0,
                                               const float* __restrict__ b0,
                                               float* __restrict__ h) {
    __shared__ float4 sW4[32 * 64];   // [kq][j] = W0[4kq..4kq+3][j]  (32 KB)
    __shared__ float  sXT[64 * 128];  // swizzled x tile, 64 nodes x 128 f (32 KB)
    __shared__ int lcnt[NBUK];
    __shared__ int lbase[NBUK];
    if (blockIdx.x < NBUK) {
        // ---- bin edges by dst>>8 via LDS histogram; 1 global atomic per (block,bucket) ----
        for (int i = threadIdx.x; i < NBUK; i += 512) lcnt[i] = 0;
        __syncthreads();
        int e0 = blockIdx.x * CHUNK;
        int e1 = min(e0 + CHUNK, NE);
        for (int e = e0 + (int)threadIdx.x; e < e1; e += 512)
            atomicAdd(&lcnt[dst[e] >> 8], 1);
        __syncthreads();
        for (int i = threadIdx.x; i < NBUK; i += 512) {
            int c = lcnt[i];
            lbase[i] = c ? atomicAdd(&cursor[i], c) : 0;
            lcnt[i] = 0;
        }
        __syncthreads();
        for (int e = e0 + (int)threadIdx.x; e < e1; e += 512) {
            int d = dst[e];
            int s = src[e];
            int bk = d >> 8;
            int pos = lbase[bk] + atomicAdd(&lcnt[bk], 1);
            if (pos < BCAP)
                bucket[(size_t)bk * BCAP + pos] = ((unsigned)s << 8) | (unsigned)(d & 255);
        }
    } else {
        // ---- input GEMM: h = relu(x @ W0 + b0), lane = node ----
        for (int i = threadIdx.x; i < 32 * 64; i += 512) {
            const float* wp = W0 + ((i >> 6) << 8) + (i & 63);   // W0[4kq][j]
            sW4[i] = make_float4(wp[0], wp[64], wp[128], wp[192]);
        }
        int lane = threadIdx.x & 63;
        int jw   = (threadIdx.x >> 6) << 3;          // wave's 8-col slice
        float bj0 = b0[jw + 0], bj1 = b0[jw + 1], bj2 = b0[jw + 2], bj3 = b0[jw + 3];
        float bj4 = b0[jw + 4], bj5 = b0[jw + 5], bj6 = b0[jw + 6], bj7 = b0[jw + 7];
        for (int t = blockIdx.x - NBUK; t < NTILE; t += GB) {
            int n0 = t << 6;
            __syncthreads();                          // sXT free (also covers sW4 1st iter)
            for (int i = threadIdx.x; i < 64 * 32; i += 512) {   // i = float4 index
                int r = i >> 5, kq = i & 31;
                int n = n0 + r;
                float4 v = make_float4(0.f, 0.f, 0.f, 0.f);
                if (n < NN) v = *(const float4*)(x + ((size_t)n << 7) + (kq << 2));
                *(float4*)((char*)sXT + (r << 9) + ((kq << 4) ^ ((r & 7) << 4))) = v;
            }
            __syncthreads();
            float a0 = bj0, a1 = bj1, a2 = bj2, a3 = bj3;
            float a4 = bj4, a5 = bj5, a6 = bj6, a7 = bj7;
#pragma unroll 4
            for (int kq = 0; kq < 32; ++kq) {
                float4 xv = *(const float4*)((char*)sXT + (lane << 9)
                                             + ((kq << 4) ^ ((lane & 7) << 4)));
                const float4* wrow = sW4 + (kq << 6) + jw;      // broadcast reads
                float4 w;
                w = wrow[0]; a0 = fmaf(xv.w,w.w,fmaf(xv.z,w.z,fmaf(xv.y,w.y,fmaf(xv.x,w.x,a0))));
                w = wrow[1]; a1 = fmaf(xv.w,w.w,fmaf(xv.z,w.z,fmaf(xv.y,w.y,fmaf(xv.x,w.x,a1))));
                w = wrow[2]; a2 = fmaf(xv.w,w.w,fmaf(xv.z,w.z,fmaf(xv.y,w.y,fmaf(xv.x,w.x,a2))));
                w = wrow[3]; a3 = fmaf(xv.w,w.w,fmaf(xv.z,w.z,fmaf(xv.y,w.y,fmaf(xv.x,w.x,a3))));
                w = wrow[4]; a4 = fmaf(xv.w,w.w,fmaf(xv.z,w.z,fmaf(xv.y,w.y,fmaf(xv.x,w.x,a4))));
                w = wrow[5]; a5 = fmaf(xv.w,w.w,fmaf(xv.z,w.z,fmaf(xv.y,w.y,fmaf(xv.x,w.x,a5))));
                w = wrow[6]; a6 = fmaf(xv.w,w.w,fmaf(xv.z,w.z,fmaf(xv.y,w.y,fmaf(xv.x,w.x,a6))));
                w = wrow[7]; a7 = fmaf(xv.w,w.w,fmaf(xv.z,w.z,fmaf(xv.y,w.y,fmaf(xv.x,w.x,a7))));
            }
            int n = n0 + lane;
            if (n < NN) {
                float* hp = h + ((size_t)n << 6) + jw;
                *(float4*)hp       = make_float4(fmaxf(a0,0.f), fmaxf(a1,0.f),
                                                 fmaxf(a2,0.f), fmaxf(a3,0.f));
                *(float4*)(hp + 4) = make_float4(fmaxf(a4,0.f), fmaxf(a5,0.f),
                                                 fmaxf(a6,0.f), fmaxf(a7,0.f));
            }
        }
    }
}

// ---- gemmLR body: g(bf16) = h@Wl ; r(fp32,in-place) = h@Wr + bl ----
// lane=node; h tile staged to LDS (coalesced, XOR-swizzled); Wl/Wr broadcast from LDS.
__device__ __forceinline__ void gemmLR_body(float4* sWL, float4* sWR, float* sXT,
                                            int tid, int nblk, int bidx,
                                            float* __restrict__ h_r,
                                            __hip_bfloat16* __restrict__ g,
                                            const float* __restrict__ Wl,
                                            const float* __restrict__ bl,
                                            const float* __restrict__ Wr) {
    for (int i = tid; i < 16 * 64; i += 256) {
        int kq = i >> 6, j = i & 63;
        const float* wl = Wl + (kq << 8) + j;
        const float* wr = Wr + (kq << 8) + j;
        sWL[i] = make_float4(wl[0], wl[64], wl[128], wl[192]);
        sWR[i] = make_float4(wr[0], wr[64], wr[128], wr[192]);
    }
    int lane = tid & 63;
    int jw   = (tid >> 6) << 4;                 // wave's 16-col slice
    float blv[16];
#pragma unroll
    for (int jj = 0; jj < 16; ++jj) blv[jj] = bl[jw + jj];
    for (int t = bidx; t < NTILE; t += nblk) {
        int n0 = t << 6;
        __syncthreads();
        for (int i = tid; i < 64 * 16; i += 256) {   // i = float4 index
            int r = i >> 4, kq = i & 15;
            int n = n0 + r;
            float4 v = make_float4(0.f, 0.f, 0.f, 0.f);
            if (n < NN) v = *(const float4*)(h_r + ((size_t)n << 6) + (kq << 2));
            *(float4*)((char*)sXT + (r << 8) + ((kq << 4) ^ ((r & 7) << 4))) = v;
        }
        __syncthreads();
        float al[16], ar[16];
#pragma unroll
        for (int jj = 0; jj < 16; ++jj) { al[jj] = 0.f; ar[jj] = 0.f; }
#pragma unroll 2
        for (int kq = 0; kq < 16; ++kq) {
            float4 xv = *(const float4*)((char*)sXT + (lane << 8)
                                         + ((kq << 4) ^ ((lane & 7) << 4)));
            const float4* wlr = sWL + (kq << 6) + jw;
            const float4* wrr = sWR + (kq << 6) + jw;
#pragma unroll
            for (int jj = 0; jj < 16; ++jj) {
                float4 wl = wlr[jj], wr = wrr[jj];
                al[jj] = fmaf(xv.w,wl.w,fmaf(xv.z,wl.z,fmaf(xv.y,wl.y,fmaf(xv.x,wl.x,al[jj]))));
                ar[jj] = fmaf(xv.w,wr.w,fmaf(xv.z,wr.z,fmaf(xv.y,wr.y,fmaf(xv.x,wr.x,ar[jj]))));
            }
        }
        int n = n0 + lane;
        if (n < NN) {
            unsigned short us[16];
#pragma unroll
            for (int jj = 0; jj < 16; ++jj) us[jj] = f2bf(al[jj]);
            uint4 u0, u1;
            u0.x = (unsigned)us[0]  | ((unsigned)us[1]  << 16);
            u0.y = (unsigned)us[2]  | ((unsigned)us[3]  << 16);
            u0.z = (unsigned)us[4]  | ((unsigned)us[5]  << 16);
            u0.w = (unsigned)us[6]  | ((unsigned)us[7]  << 16);
            u1.x = (unsigned)us[8]  | ((unsigned)us[9]  << 16);
            u1.y = (unsigned)us[10] | ((unsigned)us[11] << 16);
            u1.z = (unsigned)us[12] | ((unsigned)us[13] << 16);
            u1.w = (unsigned)us[14] | ((unsigned)us[15] << 16);
            char* gp = (char*)g + ((size_t)n << 7) + ((size_t)jw << 1);
            *(uint4*)gp        = u0;
            *(uint4*)(gp + 16) = u1;
            float* rp = h_r + ((size_t)n << 6) + jw;
            *(float4*)(rp)      = make_float4(ar[0]+blv[0],  ar[1]+blv[1],
                                              ar[2]+blv[2],  ar[3]+blv[3]);
            *(float4*)(rp + 4)  = make_float4(ar[4]+blv[4],  ar[5]+blv[5],
                                              ar[6]+blv[6],  ar[7]+blv[7]);
            *(float4*)(rp + 8)  = make_float4(ar[8]+blv[8],  ar[9]+blv[9],
                                              ar[10]+blv[10],ar[11]+blv[11]);
            *(float4*)(rp + 12) = make_float4(ar[12]+blv[12],ar[13]+blv[13],
                                              ar[14]+blv[14],ar[15]+blv[15]);
        }
    }
}

// ============ fused: phase-2 ELL build (blocks 0..NBUK) || gemmLR layer 0 ============
#define MGB 1024
__global__ void __launch_bounds__(256) k_mid(const unsigned int* __restrict__ bucket,
                                             const int* __restrict__ cursor,
                                             int* __restrict__ cnt,
                                             int* __restrict__ ell,
                                             float* __restrict__ h_r,
                                             __hip_bfloat16* __restrict__ g,
                                             const float* __restrict__ Wl,
                                             const float* __restrict__ bl,
                                             const float* __restrict__ Wr) {
    __shared__ float4 sWL[16 * 64];
    __shared__ float4 sWR[16 * 64];
    __shared__ float  sXT[64 * 64];
    __shared__ int lc[256];
    if (blockIdx.x < NBUK) {
        lc[threadIdx.x] = 0;
        int b = blockIdx.x;
        int4* ep = (int4*)(ell + (((size_t)b << 8) * MAXD));
        for (int i = threadIdx.x; i < (256 * MAXD) / 4; i += 256)
            ep[i] = make_int4(NN, NN, NN, NN);          // sentinel -> zero row of G
        __syncthreads();
        int m = min(cursor[b], BCAP);
        const unsigned int* bp = bucket + (size_t)b * BCAP;
        for (int i = threadIdx.x; i < m; i += 256) {
            unsigned v = bp[i];
            int dlo = (int)(v & 255u);
            int s   = (int)(v >> 8);
            int p   = atomicAdd(&lc[dlo], 1);           // LDS atomic
            if (p < MAXD)
                ell[(((size_t)b << 8) + dlo) * MAXD + p] = s;
        }
        __syncthreads();
        int n = (b << 8) + (int)threadIdx.x;
        if (n < NN) cnt[n] = lc[threadIdx.x];
    } else {
        gemmLR_body(sWL, sWR, sXT, threadIdx.x, MGB, blockIdx.x - NBUK,
                    h_r, g, Wl, bl, Wr);
    }
}

// ============ standalone gemmLR (layers 1,2) ============
__global__ void __launch_bounds__(256) k_gemmLR(float* __restrict__ h_r,
                                                __hip_bfloat16* __restrict__ g,
                                                const float* __restrict__ Wl,
                                                const float* __restrict__ bl,
                                                const float* __restrict__ Wr) {
    __shared__ float4 sWL[16 * 64];
    __shared__ float4 sWR[16 * 64];
    __shared__ float  sXT[64 * 64];
    gemmLR_body(sWL, sWR, sXT, threadIdx.x, gridDim.x, blockIdx.x, h_r, g, Wl, bl, Wr);
}

// ============ gather: 2 nodes/wave, 4 B/lane (bf16x2), sentinel-padded, 8-way ILP ====
__global__ void __launch_bounds__(256) k_gather(const unsigned int* __restrict__ g2,
                                                float* __restrict__ r_h,
                                                const int* __restrict__ cnt,
                                                const int* __restrict__ ell) {
    int lane = threadIdx.x & 63;
    int half = lane >> 5;
    int col  = lane & 31;
    int wv = __builtin_amdgcn_readfirstlane((int)((blockIdx.x * 256 + threadIdx.x) >> 6));
    int nw = (gridDim.x * 256) >> 6;
    for (int p = wv; p < NN / 2; p += nw) {
        int nA = 2 * p, nB = nA + 1;
        int dgA = cnt[nA], dgB = cnt[nB];               // wave-uniform scalar loads
        int myn  = half ? nB : nA;
        int mydg = half ? dgB : dgA;
        int maxd = min(max(dgA, dgB), MAXD);
        int iters = (maxd + 7) & ~7;                    // pad to 8; sentinels add 0
        int idx0 = ell[(size_t)myn * MAXD + col];
        int idx1 = NN;
        if (iters > 32) idx1 = ell[(size_t)myn * MAXD + 32 + col];
        float L0=0.f,L1=0.f,L2=0.f,L3=0.f,L4=0.f,L5=0.f,L6=0.f,L7=0.f;
        float H0=0.f,H1=0.f,H2=0.f,H3=0.f,H4=0.f,H5=0.f,H6=0.f,H7=0.f;
        int it0 = min(iters, 32);
        for (int j = 0; j < it0; j += 8) {
            int i0 = __shfl(idx0, half * 32 + j);
            int i1 = __shfl(idx0, half * 32 + j + 1);
            int i2 = __shfl(idx0, half * 32 + j + 2);
            int i3 = __shfl(idx0, half * 32 + j + 3);
            int i4 = __shfl(idx0, half * 32 + j + 4);
            int i5 = __shfl(idx0, half * 32 + j + 5);
            int i6 = __shfl(idx0, half * 32 + j + 6);
            int i7 = __shfl(idx0, half * 32 + j + 7);
            unsigned u0 = g2[(size_t)i0 * 32 + col];
            unsigned u1 = g2[(size_t)i1 * 32 + col];
            unsigned u2 = g2[(size_t)i2 * 32 + col];
            unsigned u3 = g2[(size_t)i3 * 32 + col];
            unsigned u4 = g2[(size_t)i4 * 32 + col];
            unsigned u5 = g2[(size_t)i5 * 32 + col];
            unsigned u6 = g2[(size_t)i6 * 32 + col];
            unsigned u7 = g2[(size_t)i7 * 32 + col];
            L0 += __uint_as_float(u0 << 16); H0 += __uint_as_float(u0 & 0xffff0000u);
            L1 += __uint_as_float(u1 << 16); H1 += __uint_as_float(u1 & 0xffff0000u);
            L2 += __uint_as_float(u2 << 16); H2 += __uint_as_float(u2 & 0xffff0000u);
            L3 += __uint_as_float(u3 << 16); H3 += __uint_as_float(u3 & 0xffff0000u);
            L4 += __uint_as_float(u4 << 16); H4 += __uint_as_float(u4 & 0xffff0000u);
            L5 += __uint_as_float(u5 << 16); H5 += __uint_as_float(u5 & 0xffff0000u);
            L6 += __uint_as_float(u6 << 16); H6 += __uint_as_float(u6 & 0xffff0000u);
            L7 += __uint_as_float(u7 << 16); H7 += __uint_as_float(u7 & 0xffff0000u);
        }
        for (int j = 0; j < iters - 32; j += 8) {
            int i0 = __shfl(idx1, half * 32 + j);
            int i1 = __shfl(idx1, half * 32 + j + 1);
            int i2 = __shfl(idx1, half * 32 + j + 2);
            int i3 = __shfl(idx1, half * 32 + j + 3);
            int i4 = __shfl(idx1, half * 32 + j + 4);
            int i5 = __shfl(idx1, half * 32 + j + 5);
            int i6 = __shfl(idx1, half * 32 + j + 6);
            int i7 = __shfl(idx1, half * 32 + j + 7);
            unsigned u0 = g2[(size_t)i0 * 32 + col];
            unsigned u1 = g2[(size_t)i1 * 32 + col];
            unsigned u2 = g2[(size_t)i2 * 32 + col];
            unsigned u3 = g2[(size_t)i3 * 32 + col];
            unsigned u4 = g2[(size_t)i4 * 32 + col];
            unsigned u5 = g2[(size_t)i5 * 32 + col];
            unsigned u6 = g2[(size_t)i6 * 32 + col];
            unsigned u7 = g2[(size_t)i7 * 32 + col];
            L0 += __uint_as_float(u0 << 16); H0 += __uint_as_float(u0 & 0xffff0000u);
            L1 += __uint_as_float(u1 << 16); H1 += __uint_as_float(u1 & 0xffff0000u);
            L2 += __uint_as_float(u2 << 16); H2 += __uint_as_float(u2 & 0xffff0000u);
            L3 += __uint_as_float(u3 << 16); H3 += __uint_as_float(u3 & 0xffff0000u);
            L4 += __uint_as_float(u4 << 16); H4 += __uint_as_float(u4 & 0xffff0000u);
            L5 += __uint_as_float(u5 << 16); H5 += __uint_as_float(u5 & 0xffff0000u);
            L6 += __uint_as_float(u6 << 16); H6 += __uint_as_float(u6 & 0xffff0000u);
            L7 += __uint_as_float(u7 << 16); H7 += __uint_as_float(u7 & 0xffff0000u);
        }
        float inv  = 1.0f / fmaxf((float)mydg, 1.0f);
        float sumL = ((L0 + L1) + (L2 + L3)) + ((L4 + L5) + (L6 + L7));
        float sumH = ((H0 + H1) + (H2 + H3)) + ((H4 + H5) + (H6 + H7));
        float2* rp = (float2*)r_h + (size_t)myn * 32 + col;
        float2 rv = *rp;
        rv.x = fmaxf(fmaf(sumL, inv, rv.x), 0.0f);
        rv.y = fmaxf(fmaf(sumH, inv, rv.y), 0.0f);
        *rp = rv;
    }
}

// ============ pooling (batch sorted -> run accumulate) ============
__global__ void __launch_bounds__(256) k_pool(const int* __restrict__ batch,
                                              const float* __restrict__ h,
                                              float* __restrict__ pool,
                                              float* __restrict__ cntg) {
    int lane = threadIdx.x & 63;
    int wid  = (blockIdx.x * 256 + threadIdx.x) >> 6;
    int nw   = (gridDim.x * 256) >> 6;
    int chunk = (NN + nw - 1) / nw;
    int n0 = wid * chunk;
    if (n0 >= NN) return;
    int n1 = min(n0 + chunk, NN);
    int cur = batch[n0];
    float acc = 0.0f, acc_c = 0.0f;
    for (int n = n0; n < n1; ++n) {
        int b = batch[n];
        if (b != cur) {
            atomicAdd(&pool[(size_t)cur * 64 + lane], acc);
            if (lane == 0) atomicAdd(&cntg[cur], acc_c);
            acc = 0.0f; acc_c = 0.0f; cur = b;
        }
        acc   += h[(size_t)n * 64 + lane];
        acc_c += 1.0f;
    }
    atomicAdd(&pool[(size_t)cur * 64 + lane], acc);
    if (lane == 0) atomicAdd(&cntg[cur], acc_c);
}

// ============ output GEMM ============
__global__ void __launch_bounds__(256) k_out(const float* __restrict__ pool,
                                             const float* __restrict__ cntg,
                                             const float* __restrict__ W1,
                                             const float* __restrict__ b1,
                                             float* __restrict__ out) {
    __shared__ float sW[64 * 64];
    for (int i = threadIdx.x; i < 64 * 64; i += 256) sW[i] = W1[i];
    __syncthreads();
    int lane = threadIdx.x & 63;
    int wid  = (blockIdx.x * 256 + threadIdx.x) >> 6;
    int nw   = (gridDim.x * 256) >> 6;
    for (int gidx = wid; gidx < NG; gidx += nw) {
        float ic = 1.0f / fmaxf(cntg[gidx], 1.0f);
        float acc = 0.0f;
#pragma unroll
        for (int k = 0; k < 64; ++k)
            acc = fmaf(pool[(size_t)gidx * 64 + k], sW[k * 64 + lane], acc);
        out[(size_t)gidx * 64 + lane] = fmaf(acc, ic, b1[lane]);
    }
}

extern "C" void kernel_launch(void* const* d_in, const int* in_sizes, int n_in,
                              void* d_out, int out_size, void* d_ws, size_t ws_size,
                              hipStream_t stream) {
    const float* x     = (const float*)d_in[0];
    const int*   ei    = (const int*)d_in[1];   // [2,E]
    const int*   batch = (const int*)d_in[3];
    const float* W0    = (const float*)d_in[4];
    const float* b0    = (const float*)d_in[5];
    const float* Wl    = (const float*)d_in[6];
    const float* bl    = (const float*)d_in[7];
    const float* Wr    = (const float*)d_in[8];
    const float* W1    = (const float*)d_in[9];
    const float* b1    = (const float*)d_in[10];
    float* out = (float*)d_out;

    char* ws = (char*)d_ws;
    size_t off = 0;
    auto alloc = [&](size_t bytes) -> void* {
        void* p = ws + off;
        off += (bytes + 255) & ~(size_t)255;
        return p;
    };
    float*          A      = (float*)alloc((size_t)NN * 64 * 4);          // h / r / h'
    __hip_bfloat16* G      = (__hip_bfloat16*)alloc((size_t)NN * 64 * 2); // g (bf16), NN rows
    // zero region starts EXACTLY at G's row NN (sentinel zero row), then cursor/pool/cntg
    size_t zstart = off;
    (void)alloc((size_t)MAXD * 2);                                        // G zero row (128 B)
    int*   cursor = (int*)alloc((size_t)NBUK * 4);
    float* pool   = (float*)alloc((size_t)NG * 64 * 4);
    float* cntg   = (float*)alloc((size_t)NG * 4);
    size_t zlen = off - zstart;
    int*          ell    = (int*)alloc((size_t)NBUK * 256 * MAXD * 4);    // padded ELL
    unsigned int* bucket = (unsigned int*)alloc((size_t)NBUK * BCAP * 4);
    int*          cnt    = (int*)alloc((size_t)NN * 4);                   // fully written

    const int* src = ei;
    const int* dst = ei + NE;

    hipMemsetAsync(ws + zstart, 0, zlen, stream);

    // phase-1 binning || input projection
    k_front<<<NBUK + GB, 512, 0, stream>>>(src, dst, cursor, bucket, x, W0, b0, A);
    // phase-2 ELL build || gemmLR layer 0
    k_mid<<<NBUK + MGB, 256, 0, stream>>>(bucket, cursor, cnt, ell, A, G,
                                          Wl, bl, Wr);
    k_gather<<<4096, 256, 0, stream>>>((const unsigned int*)G, A, cnt, ell);

    for (int l = 1; l < 3; ++l) {
        k_gemmLR<<<1024, 256, 0, stream>>>(A, G,
                                           Wl + (size_t)l * 64 * 64,
                                           bl + (size_t)l * 64,
                                           Wr + (size_t)l * 64 * 64);
        k_gather<<<4096, 256, 0, stream>>>((const unsigned int*)G, A, cnt, ell);
    }

    k_pool<<<256, 256, 0, stream>>>(batch, A, pool, cntg);
    k_out<<<128, 256, 0, stream>>>(pool, cntg, W1, b1, out);
}

// Round 3
// 388.281 us; speedup vs baseline: 1.3510x; 1.2317x over previous
//
#include <hip/hip_runtime.h>
#include <hip/hip_bf16.h>

#define NN 100000
#define NE 1600000
#define DIN 128
#define NG 512
#define MAXD 64
#define NBUK 391               // dst>>8 buckets (256 nodes each)
#define BCAP 5120              // mean 4092, +16 sigma
#define CHUNK ((NE + NBUK - 1) / NBUK)
#define NTILE ((NN + 63) >> 6)  // 64-node tiles

typedef __attribute__((ext_vector_type(8))) __bf16 bf16x8;
typedef __attribute__((ext_vector_type(4))) float f32x4;

static __device__ __forceinline__ unsigned short bfhi(float f) {
    __hip_bfloat16 h = __float2bfloat16(f);
    return *reinterpret_cast<unsigned short*>(&h);
}
static __device__ __forceinline__ float bf2f(unsigned short u) {
    unsigned v = (unsigned)u << 16;
    return __uint_as_float(v);
}
static __device__ __forceinline__ bf16x8 ldfrag(const unsigned short* p) {
    bf16x8 r;
    __builtin_memcpy(&r, p, 16);
    return r;
}

// Fragment addressing (mfma_f32_16x16x32_bf16):
//  A: lane l holds A[R0 + (l&15)][32*ks + 8*(l>>4) + j], j=0..7
//  B: lane l holds B[32*ks + 8*(l>>4) + j][C0 + (l&15)]
//  C/D: col = C0 + (lane&15), row = R0 + (lane>>4)*4 + reg   [verified layout]
// LDS frag order: addr_shorts = ((slot*64 + lane)*8 + j), slot = ks*4 + rb/cb.

// ============ fused: phase-1 binning (blocks 0..NBUK) || input GEMM (rest) ============
#define GB 256
__global__ void __launch_bounds__(512) k_front(const int* __restrict__ src,
                                               const int* __restrict__ dst,
                                               int* __restrict__ cursor,
                                               unsigned int* __restrict__ bucket,
                                               const float* __restrict__ x,
                                               const float* __restrict__ W0,
                                               const float* __restrict__ b0,
                                               float* __restrict__ h) {
    __shared__ unsigned short sA0[16 * 64 * 8];   // x hi plane, frag order (16 KB)
    __shared__ unsigned short sA1[16 * 64 * 8];   // x lo plane
    __shared__ unsigned short sB0[16 * 64 * 8];   // W0 hi plane
    __shared__ unsigned short sB1[16 * 64 * 8];   // W0 lo plane
    __shared__ int lcnt[NBUK];
    __shared__ int lbase[NBUK];
    if (blockIdx.x < NBUK) {
        // ---- bin edges by dst>>8 via LDS histogram; 1 global atomic per (block,bucket) ----
        for (int i = threadIdx.x; i < NBUK; i += 512) lcnt[i] = 0;
        __syncthreads();
        int e0 = blockIdx.x * CHUNK;
        int e1 = min(e0 + CHUNK, NE);
        for (int e = e0 + (int)threadIdx.x; e < e1; e += 512)
            atomicAdd(&lcnt[dst[e] >> 8], 1);
        __syncthreads();
        for (int i = threadIdx.x; i < NBUK; i += 512) {
            int c = lcnt[i];
            lbase[i] = c ? atomicAdd(&cursor[i], c) : 0;
            lcnt[i] = 0;
        }
        __syncthreads();
        for (int e = e0 + (int)threadIdx.x; e < e1; e += 512) {
            int d = dst[e];
            int s = src[e];
            int bk = d >> 8;
            int pos = lbase[bk] + atomicAdd(&lcnt[bk], 1);
            if (pos < BCAP)
                bucket[(size_t)bk * BCAP + pos] = ((unsigned)s << 8) | (unsigned)(d & 255);
        }
    } else {
        // ---- input GEMM via MFMA bf16x3: h = relu(x @ W0 + b0) ----
        // prepack W0 into fragment order, hi/lo planes
        for (int i = threadIdx.x; i < 8192; i += 512) {
            int k = i >> 6, c = i & 63;
            int slot = ((k >> 5) << 2) | (c >> 4);
            int ln   = (((k >> 3) & 3) << 4) | (c & 15);
            int addr = (((slot << 6) | ln) << 3) | (k & 7);
            float w0 = W0[i];
            unsigned short hh = bfhi(w0);
            sB0[addr] = hh;
            sB1[addr] = bfhi(w0 - bf2f(hh));
        }
        int lane = threadIdx.x & 63;
        int wv   = threadIdx.x >> 6;          // 8 waves
        int cb   = wv & 3;                    // 16-col block
        int rbh  = wv >> 2;                   // row half: rb in {2*rbh, 2*rbh+1}
        int col  = (cb << 4) | (lane & 15);
        float bj = b0[col];
        int r0   = (lane >> 4) << 2;
        for (int t = blockIdx.x - NBUK; t < NTILE; t += GB) {
            int n0 = t << 6;
            __syncthreads();                  // sA free (also covers sB prepack, 1st iter)
#pragma unroll
            for (int i = 0; i < 4; ++i) {     // stage 64x128 x-tile -> hi/lo frags
                int tau = (int)threadIdx.x + (i << 9);
                int r = tau >> 5, kq = tau & 31;
                int n = n0 + r;
                float4 v = make_float4(0.f, 0.f, 0.f, 0.f);
                if (n < NN) v = *(const float4*)(x + ((size_t)n << 7) + (kq << 2));
                int k0   = kq << 2;
                int slot = ((k0 >> 5) << 2) | (r >> 4);
                int ln   = (((k0 >> 3) & 3) << 4) | (r & 15);
                int base = (((slot << 6) | ln) << 3) | (k0 & 7);
                unsigned short h0 = bfhi(v.x), h1 = bfhi(v.y),
                               h2 = bfhi(v.z), h3 = bfhi(v.w);
                *(ushort4*)(&sA0[base]) = make_ushort4(h0, h1, h2, h3);
                *(ushort4*)(&sA1[base]) = make_ushort4(
                    bfhi(v.x - bf2f(h0)), bfhi(v.y - bf2f(h1)),
                    bfhi(v.z - bf2f(h2)), bfhi(v.w - bf2f(h3)));
            }
            __syncthreads();
            f32x4 acc[2] = {{0.f,0.f,0.f,0.f},{0.f,0.f,0.f,0.f}};
#pragma unroll
            for (int ks = 0; ks < 4; ++ks) {
                int bbase = ((((ks << 2) | cb) << 6) | lane) << 3;
                bf16x8 bh = ldfrag(&sB0[bbase]);
                bf16x8 bl_ = ldfrag(&sB1[bbase]);
#pragma unroll
                for (int rl = 0; rl < 2; ++rl) {
                    int rb = (rbh << 1) | rl;
                    int abase = ((((ks << 2) | rb) << 6) | lane) << 3;
                    bf16x8 ah = ldfrag(&sA0[abase]);
                    bf16x8 al = ldfrag(&sA1[abase]);
                    acc[rl] = __builtin_amdgcn_mfma_f32_16x16x32_bf16(ah, bh,  acc[rl], 0, 0, 0);
                    acc[rl] = __builtin_amdgcn_mfma_f32_16x16x32_bf16(ah, bl_, acc[rl], 0, 0, 0);
                    acc[rl] = __builtin_amdgcn_mfma_f32_16x16x32_bf16(al, bh,  acc[rl], 0, 0, 0);
                }
            }
#pragma unroll
            for (int rl = 0; rl < 2; ++rl) {
                int rb = (rbh << 1) | rl;
#pragma unroll
                for (int reg = 0; reg < 4; ++reg) {
                    int row = (rb << 4) + r0 + reg;
                    int n = n0 + row;
                    if (n < NN)
                        h[((size_t)n << 6) + col] = fmaxf(acc[rl][reg] + bj, 0.f);
                }
            }
        }
    }
}

// ---- gemmLR via MFMA bf16x3: g(bf16) = h@Wl ; r(fp32,in-place) = h@Wr + bl ----
__device__ __forceinline__ void gemmLR_mfma(unsigned short* sA0, unsigned short* sA1,
                                            unsigned short* sBL0, unsigned short* sBL1,
                                            unsigned short* sBR0, unsigned short* sBR1,
                                            int tid, int nblk, int bidx,
                                            float* __restrict__ h_r,
                                            __hip_bfloat16* __restrict__ g,
                                            const float* __restrict__ Wl,
                                            const float* __restrict__ bl,
                                            const float* __restrict__ Wr) {
    // prepack Wl/Wr into fragment order, hi/lo planes (once per block)
    for (int i = tid; i < 4096; i += 256) {
        int k = i >> 6, c = i & 63;
        int slot = ((k >> 5) << 2) | (c >> 4);
        int ln   = (((k >> 3) & 3) << 4) | (c & 15);
        int addr = (((slot << 6) | ln) << 3) | (k & 7);
        float wl = Wl[i];
        unsigned short hl = bfhi(wl);
        sBL0[addr] = hl;
        sBL1[addr] = bfhi(wl - bf2f(hl));
        float wr = Wr[i];
        unsigned short hr = bfhi(wr);
        sBR0[addr] = hr;
        sBR1[addr] = bfhi(wr - bf2f(hr));
    }
    int lane = tid & 63;
    int cb   = tid >> 6;                    // 4 waves = 4 col-blocks
    int col  = (cb << 4) | (lane & 15);
    float bj = bl[col];
    int r0   = (lane >> 4) << 2;
    unsigned short* gp = (unsigned short*)g;
    for (int t = bidx; t < NTILE; t += nblk) {
        int n0 = t << 6;
        __syncthreads();
#pragma unroll
        for (int i = 0; i < 4; ++i) {       // stage 64x64 h-tile -> hi/lo frags
            int tau = tid + (i << 8);
            int r = tau >> 4, kq = tau & 15;
            int n = n0 + r;
            float4 v = make_float4(0.f, 0.f, 0.f, 0.f);
            if (n < NN) v = *(const float4*)(h_r + ((size_t)n << 6) + (kq << 2));
            int k0   = kq << 2;
            int slot = ((k0 >> 5) << 2) | (r >> 4);
            int ln   = (((k0 >> 3) & 3) << 4) | (r & 15);
            int base = (((slot << 6) | ln) << 3) | (k0 & 7);
            unsigned short h0 = bfhi(v.x), h1 = bfhi(v.y),
                           h2 = bfhi(v.z), h3 = bfhi(v.w);
            *(ushort4*)(&sA0[base]) = make_ushort4(h0, h1, h2, h3);
            *(ushort4*)(&sA1[base]) = make_ushort4(
                bfhi(v.x - bf2f(h0)), bfhi(v.y - bf2f(h1)),
                bfhi(v.z - bf2f(h2)), bfhi(v.w - bf2f(h3)));
        }
        __syncthreads();
        f32x4 accl[4] = {{0.f,0.f,0.f,0.f},{0.f,0.f,0.f,0.f},
                         {0.f,0.f,0.f,0.f},{0.f,0.f,0.f,0.f}};
        f32x4 accr[4] = {{0.f,0.f,0.f,0.f},{0.f,0.f,0.f,0.f},
                         {0.f,0.f,0.f,0.f},{0.f,0.f,0.f,0.f}};
#pragma unroll
        for (int ks = 0; ks < 2; ++ks) {
            int bbase = ((((ks << 2) | cb) << 6) | lane) << 3;
            bf16x8 bLh = ldfrag(&sBL0[bbase]);
            bf16x8 bLl = ldfrag(&sBL1[bbase]);
            bf16x8 bRh = ldfrag(&sBR0[bbase]);
            bf16x8 bRl = ldfrag(&sBR1[bbase]);
#pragma unroll
            for (int rb = 0; rb < 4; ++rb) {
                int abase = ((((ks << 2) | rb) << 6) | lane) << 3;
                bf16x8 ah = ldfrag(&sA0[abase]);
                bf16x8 al = ldfrag(&sA1[abase]);
                accl[rb] = __builtin_amdgcn_mfma_f32_16x16x32_bf16(ah, bLh, accl[rb], 0, 0, 0);
                accl[rb] = __builtin_amdgcn_mfma_f32_16x16x32_bf16(ah, bLl, accl[rb], 0, 0, 0);
                accl[rb] = __builtin_amdgcn_mfma_f32_16x16x32_bf16(al, bLh, accl[rb], 0, 0, 0);
                accr[rb] = __builtin_amdgcn_mfma_f32_16x16x32_bf16(ah, bRh, accr[rb], 0, 0, 0);
                accr[rb] = __builtin_amdgcn_mfma_f32_16x16x32_bf16(ah, bRl, accr[rb], 0, 0, 0);
                accr[rb] = __builtin_amdgcn_mfma_f32_16x16x32_bf16(al, bRh, accr[rb], 0, 0, 0);
            }
        }
#pragma unroll
        for (int rb = 0; rb < 4; ++rb) {
#pragma unroll
            for (int reg = 0; reg < 4; ++reg) {
                int row = (rb << 4) + r0 + reg;
                int n = n0 + row;
                if (n < NN) {
                    size_t o = ((size_t)n << 6) + col;
                    gp[o]  = bfhi(accl[rb][reg]);
                    h_r[o] = accr[rb][reg] + bj;
                }
            }
        }
    }
}

// ============ fused: phase-2 ELL build (blocks 0..NBUK) || gemmLR layer 0 ============
#define MGB 512
__global__ void __launch_bounds__(256) k_mid(const unsigned int* __restrict__ bucket,
                                             const int* __restrict__ cursor,
                                             int* __restrict__ cnt,
                                             int* __restrict__ ell,
                                             float* __restrict__ h_r,
                                             __hip_bfloat16* __restrict__ g,
                                             const float* __restrict__ Wl,
                                             const float* __restrict__ bl,
                                             const float* __restrict__ Wr) {
    __shared__ unsigned short sA0[8 * 64 * 8];
    __shared__ unsigned short sA1[8 * 64 * 8];
    __shared__ unsigned short sBL0[8 * 64 * 8];
    __shared__ unsigned short sBL1[8 * 64 * 8];
    __shared__ unsigned short sBR0[8 * 64 * 8];
    __shared__ unsigned short sBR1[8 * 64 * 8];
    __shared__ int lc[256];
    if (blockIdx.x < NBUK) {
        lc[threadIdx.x] = 0;
        int b = blockIdx.x;
        int4* ep = (int4*)(ell + (((size_t)b << 8) * MAXD));
        for (int i = threadIdx.x; i < (256 * MAXD) / 4; i += 256)
            ep[i] = make_int4(NN, NN, NN, NN);          // sentinel -> zero row of G
        __syncthreads();
        int m = min(cursor[b], BCAP);
        const unsigned int* bp = bucket + (size_t)b * BCAP;
        for (int i = threadIdx.x; i < m; i += 256) {
            unsigned v = bp[i];
            int dlo = (int)(v & 255u);
            int s   = (int)(v >> 8);
            int p   = atomicAdd(&lc[dlo], 1);           // LDS atomic
            if (p < MAXD)
                ell[(((size_t)b << 8) + dlo) * MAXD + p] = s;
        }
        __syncthreads();
        int n = (b << 8) + (int)threadIdx.x;
        if (n < NN) cnt[n] = lc[threadIdx.x];
    } else {
        gemmLR_mfma(sA0, sA1, sBL0, sBL1, sBR0, sBR1,
                    threadIdx.x, MGB, blockIdx.x - NBUK, h_r, g, Wl, bl, Wr);
    }
}

// ============ standalone gemmLR (layers 1,2) ============
__global__ void __launch_bounds__(256) k_gemmLR(float* __restrict__ h_r,
                                                __hip_bfloat16* __restrict__ g,
                                                const float* __restrict__ Wl,
                                                const float* __restrict__ bl,
                                                const float* __restrict__ Wr) {
    __shared__ unsigned short sA0[8 * 64 * 8];
    __shared__ unsigned short sA1[8 * 64 * 8];
    __shared__ unsigned short sBL0[8 * 64 * 8];
    __shared__ unsigned short sBL1[8 * 64 * 8];
    __shared__ unsigned short sBR0[8 * 64 * 8];
    __shared__ unsigned short sBR1[8 * 64 * 8];
    gemmLR_mfma(sA0, sA1, sBL0, sBL1, sBR0, sBR1,
                threadIdx.x, gridDim.x, blockIdx.x, h_r, g, Wl, bl, Wr);
}

// ============ gather: 2 nodes/wave, 4 B/lane (bf16x2), sentinel-padded, 8-way ILP ====
__global__ void __launch_bounds__(256) k_gather(const unsigned int* __restrict__ g2,
                                                float* __restrict__ r_h,
                                                const int* __restrict__ cnt,
                                                const int* __restrict__ ell) {
    int lane = threadIdx.x & 63;
    int half = lane >> 5;
    int col  = lane & 31;
    int wv = __builtin_amdgcn_readfirstlane((int)((blockIdx.x * 256 + threadIdx.x) >> 6));
    int nw = (gridDim.x * 256) >> 6;
    for (int p = wv; p < NN / 2; p += nw) {
        int nA = 2 * p, nB = nA + 1;
        int dgA = cnt[nA], dgB = cnt[nB];               // wave-uniform scalar loads
        int myn  = half ? nB : nA;
        int mydg = half ? dgB : dgA;
        int maxd = min(max(dgA, dgB), MAXD);
        int iters = (maxd + 7) & ~7;                    // pad to 8; sentinels add 0
        int idx0 = ell[(size_t)myn * MAXD + col];
        int idx1 = NN;
        if (iters > 32) idx1 = ell[(size_t)myn * MAXD + 32 + col];
        float L0=0.f,L1=0.f,L2=0.f,L3=0.f,L4=0.f,L5=0.f,L6=0.f,L7=0.f;
        float H0=0.f,H1=0.f,H2=0.f,H3=0.f,H4=0.f,H5=0.f,H6=0.f,H7=0.f;
        int it0 = min(iters, 32);
        for (int j = 0; j < it0; j += 8) {
            int i0 = __shfl(idx0, half * 32 + j);
            int i1 = __shfl(idx0, half * 32 + j + 1);
            int i2 = __shfl(idx0, half * 32 + j + 2);
            int i3 = __shfl(idx0, half * 32 + j + 3);
            int i4 = __shfl(idx0, half * 32 + j + 4);
            int i5 = __shfl(idx0, half * 32 + j + 5);
            int i6 = __shfl(idx0, half * 32 + j + 6);
            int i7 = __shfl(idx0, half * 32 + j + 7);
            unsigned u0 = g2[(size_t)i0 * 32 + col];
            unsigned u1 = g2[(size_t)i1 * 32 + col];
            unsigned u2 = g2[(size_t)i2 * 32 + col];
            unsigned u3 = g2[(size_t)i3 * 32 + col];
            unsigned u4 = g2[(size_t)i4 * 32 + col];
            unsigned u5 = g2[(size_t)i5 * 32 + col];
            unsigned u6 = g2[(size_t)i6 * 32 + col];
            unsigned u7 = g2[(size_t)i7 * 32 + col];
            L0 += __uint_as_float(u0 << 16); H0 += __uint_as_float(u0 & 0xffff0000u);
            L1 += __uint_as_float(u1 << 16); H1 += __uint_as_float(u1 & 0xffff0000u);
            L2 += __uint_as_float(u2 << 16); H2 += __uint_as_float(u2 & 0xffff0000u);
            L3 += __uint_as_float(u3 << 16); H3 += __uint_as_float(u3 & 0xffff0000u);
            L4 += __uint_as_float(u4 << 16); H4 += __uint_as_float(u4 & 0xffff0000u);
            L5 += __uint_as_float(u5 << 16); H5 += __uint_as_float(u5 & 0xffff0000u);
            L6 += __uint_as_float(u6 << 16); H6 += __uint_as_float(u6 & 0xffff0000u);
            L7 += __uint_as_float(u7 << 16); H7 += __uint_as_float(u7 & 0xffff0000u);
        }
        for (int j = 0; j < iters - 32; j += 8) {
            int i0 = __shfl(idx1, half * 32 + j);
            int i1 = __shfl(idx1, half * 32 + j + 1);
            int i2 = __shfl(idx1, half * 32 + j + 2);
            int i3 = __shfl(idx1, half * 32 + j + 3);
            int i4 = __shfl(idx1, half * 32 + j + 4);
            int i5 = __shfl(idx1, half * 32 + j + 5);
            int i6 = __shfl(idx1, half * 32 + j + 6);
            int i7 = __shfl(idx1, half * 32 + j + 7);
            unsigned u0 = g2[(size_t)i0 * 32 + col];
            unsigned u1 = g2[(size_t)i1 * 32 + col];
            unsigned u2 = g2[(size_t)i2 * 32 + col];
            unsigned u3 = g2[(size_t)i3 * 32 + col];
            unsigned u4 = g2[(size_t)i4 * 32 + col];
            unsigned u5 = g2[(size_t)i5 * 32 + col];
            unsigned u6 = g2[(size_t)i6 * 32 + col];
            unsigned u7 = g2[(size_t)i7 * 32 + col];
            L0 += __uint_as_float(u0 << 16); H0 += __uint_as_float(u0 & 0xffff0000u);
            L1 += __uint_as_float(u1 << 16); H1 += __uint_as_float(u1 & 0xffff0000u);
            L2 += __uint_as_float(u2 << 16); H2 += __uint_as_float(u2 & 0xffff0000u);
            L3 += __uint_as_float(u3 << 16); H3 += __uint_as_float(u3 & 0xffff0000u);
            L4 += __uint_as_float(u4 << 16); H4 += __uint_as_float(u4 & 0xffff0000u);
            L5 += __uint_as_float(u5 << 16); H5 += __uint_as_float(u5 & 0xffff0000u);
            L6 += __uint_as_float(u6 << 16); H6 += __uint_as_float(u6 & 0xffff0000u);
            L7 += __uint_as_float(u7 << 16); H7 += __uint_as_float(u7 & 0xffff0000u);
        }
        float inv  = 1.0f / fmaxf((float)mydg, 1.0f);
        float sumL = ((L0 + L1) + (L2 + L3)) + ((L4 + L5) + (L6 + L7));
        float sumH = ((H0 + H1) + (H2 + H3)) + ((H4 + H5) + (H6 + H7));
        float2* rp = (float2*)r_h + (size_t)myn * 32 + col;
        float2 rv = *rp;
        rv.x = fmaxf(fmaf(sumL, inv, rv.x), 0.0f);
        rv.y = fmaxf(fmaf(sumH, inv, rv.y), 0.0f);
        *rp = rv;
    }
}

// ============ pooling (batch sorted -> run accumulate) ============
__global__ void __launch_bounds__(256) k_pool(const int* __restrict__ batch,
                                              const float* __restrict__ h,
                                              float* __restrict__ pool,
                                              float* __restrict__ cntg) {
    int lane = threadIdx.x & 63;
    int wid  = (blockIdx.x * 256 + threadIdx.x) >> 6;
    int nw   = (gridDim.x * 256) >> 6;
    int chunk = (NN + nw - 1) / nw;
    int n0 = wid * chunk;
    if (n0 >= NN) return;
    int n1 = min(n0 + chunk, NN);
    int cur = batch[n0];
    float acc = 0.0f, acc_c = 0.0f;
    for (int n = n0; n < n1; ++n) {
        int b = batch[n];
        if (b != cur) {
            atomicAdd(&pool[(size_t)cur * 64 + lane], acc);
            if (lane == 0) atomicAdd(&cntg[cur], acc_c);
            acc = 0.0f; acc_c = 0.0f; cur = b;
        }
        acc   += h[(size_t)n * 64 + lane];
        acc_c += 1.0f;
    }
    atomicAdd(&pool[(size_t)cur * 64 + lane], acc);
    if (lane == 0) atomicAdd(&cntg[cur], acc_c);
}

// ============ output GEMM ============
__global__ void __launch_bounds__(256) k_out(const float* __restrict__ pool,
                                             const float* __restrict__ cntg,
                                             const float* __restrict__ W1,
                                             const float* __restrict__ b1,
                                             float* __restrict__ out) {
    __shared__ float sW[64 * 64];
    for (int i = threadIdx.x; i < 64 * 64; i += 256) sW[i] = W1[i];
    __syncthreads();
    int lane = threadIdx.x & 63;
    int wid  = (blockIdx.x * 256 + threadIdx.x) >> 6;
    int nw   = (gridDim.x * 256) >> 6;
    for (int gidx = wid; gidx < NG; gidx += nw) {
        float ic = 1.0f / fmaxf(cntg[gidx], 1.0f);
        float acc = 0.0f;
#pragma unroll
        for (int k = 0; k < 64; ++k)
            acc = fmaf(pool[(size_t)gidx * 64 + k], sW[k * 64 + lane], acc);
        out[(size_t)gidx * 64 + lane] = fmaf(acc, ic, b1[lane]);
    }
}

extern "C" void kernel_launch(void* const* d_in, const int* in_sizes, int n_in,
                              void* d_out, int out_size, void* d_ws, size_t ws_size,
                              hipStream_t stream) {
    const float* x     = (const float*)d_in[0];
    const int*   ei    = (const int*)d_in[1];   // [2,E]
    const int*   batch = (const int*)d_in[3];
    const float* W0    = (const float*)d_in[4];
    const float* b0    = (const float*)d_in[5];
    const float* Wl    = (const float*)d_in[6];
    const float* bl    = (const float*)d_in[7];
    const float* Wr    = (const float*)d_in[8];
    const float* W1    = (const float*)d_in[9];
    const float* b1    = (const float*)d_in[10];
    float* out = (float*)d_out;

    char* ws = (char*)d_ws;
    size_t off = 0;
    auto alloc = [&](size_t bytes) -> void* {
        void* p = ws + off;
        off += (bytes + 255) & ~(size_t)255;
        return p;
    };
    float*          A      = (float*)alloc((size_t)NN * 64 * 4);          // h / r / h'
    __hip_bfloat16* G      = (__hip_bfloat16*)alloc((size_t)NN * 64 * 2); // g (bf16), NN rows
    // zero region starts EXACTLY at G's row NN (sentinel zero row), then cursor/pool/cntg
    size_t zstart = off;
    (void)alloc((size_t)MAXD * 2);                                        // G zero row (128 B)
    int*   cursor = (int*)alloc((size_t)NBUK * 4);
    float* pool   = (float*)alloc((size_t)NG * 64 * 4);
    float* cntg   = (float*)alloc((size_t)NG * 4);
    size_t zlen = off - zstart;
    int*          ell    = (int*)alloc((size_t)NBUK * 256 * MAXD * 4);    // padded ELL
    unsigned int* bucket = (unsigned int*)alloc((size_t)NBUK * BCAP * 4);
    int*          cnt    = (int*)alloc((size_t)NN * 4);                   // fully written

    const int* src = ei;
    const int* dst = ei + NE;

    hipMemsetAsync(ws + zstart, 0, zlen, stream);

    // phase-1 binning || input projection (MFMA)
    k_front<<<NBUK + GB, 512, 0, stream>>>(src, dst, cursor, bucket, x, W0, b0, A);
    // phase-2 ELL build || gemmLR layer 0 (MFMA)
    k_mid<<<NBUK + MGB, 256, 0, stream>>>(bucket, cursor, cnt, ell, A, G,
                                          Wl, bl, Wr);
    k_gather<<<4096, 256, 0, stream>>>((const unsigned int*)G, A, cnt, ell);

    for (int l = 1; l < 3; ++l) {
        k_gemmLR<<<512, 256, 0, stream>>>(A, G,
                                          Wl + (size_t)l * 64 * 64,
                                          bl + (size_t)l * 64,
                                          Wr + (size_t)l * 64 * 64);
        k_gather<<<4096, 256, 0, stream>>>((const unsigned int*)G, A, cnt, ell);
    }

    k_pool<<<256, 256, 0, stream>>>(batch, A, pool, cntg);
    k_out<<<128, 256, 0, stream>>>(pool, cntg, W1, b1, out);
}